// Round 8
// baseline (78.054 us; speedup 1.0000x reference)
//
#include <hip/hip_runtime.h>
#include <math.h>

#define D_MODEL 4096
#define D_INNER 8192
#define D_STATE 64
#define PROJ_OUT (2 * D_INNER + 2 * D_STATE + 1)  // 16513

typedef float f32x4 __attribute__((ext_vector_type(4)));

// ws layout (floats):
#define NSEG1 4
#define PP1_STRIDE 16516                 // PROJ_OUT padded to x4
#define G_OFF (NSEG1 * PP1_STRIDE)       // 66064
#define NSEG3 8

// ---------------------------------------------------------------------------
// Kernel 1: proj partials = W_in @ x, column-split 4 ways (1024-col segments).
// A/B probe vs round 7: PLAIN loads for W_in (NT hint removed) — single
// variable change to test whether nontemporal was helping (L3 protection
// for W_out) or hurting (read burst efficiency).
// ---------------------------------------------------------------------------
__global__ void __launch_bounds__(256) matvec_in_kernel(
    const float* __restrict__ W, const float* __restrict__ x,
    float* __restrict__ pp) {
    const int wave = threadIdx.x >> 6;
    const int lane = threadIdx.x & 63;
    const int seg  = blockIdx.x & (NSEG1 - 1);
    const int pair = (blockIdx.x >> 2) * 4 + wave;
    const int row0 = pair * 2;
    if (row0 >= PROJ_OUT) return;
    const int row1 = row0 + 1;
    const bool has1 = (row1 < PROJ_OUT);

    const int k0 = seg * (D_MODEL / NSEG1);  // 1024-col segment
    const float* Wr0 = W + (size_t)row0 * D_MODEL + k0;
    const float* Wr1 = has1 ? (Wr0 + D_MODEL) : Wr0;
    const float* xp  = x + k0;

    float acc0 = 0.f, acc1 = 0.f;
    #pragma unroll
    for (int k = lane * 4; k < D_MODEL / NSEG1; k += 64 * 4) {
        f32x4 xv = *reinterpret_cast<const f32x4*>(xp + k);
        f32x4 w0 = *reinterpret_cast<const f32x4*>(Wr0 + k);
        f32x4 w1 = *reinterpret_cast<const f32x4*>(Wr1 + k);
        acc0 += w0.x * xv.x + w0.y * xv.y + w0.z * xv.z + w0.w * xv.w;
        acc1 += w1.x * xv.x + w1.y * xv.y + w1.z * xv.z + w1.w * xv.w;
    }
    #pragma unroll
    for (int off = 32; off; off >>= 1) {
        acc0 += __shfl_down(acc0, off, 64);
        acc1 += __shfl_down(acc1, off, 64);
    }
    if (lane == 0) {
        pp[seg * PP1_STRIDE + row0] = acc0;
        if (has1) pp[seg * PP1_STRIDE + row1] = acc1;
    }
}

// ---------------------------------------------------------------------------
// Kernel 2: SSM update + gating; folds the 4 column-partials inline.
// Blocks 0..15 also zero out[0:4096] so kernel 3 can atomically accumulate.
// ---------------------------------------------------------------------------
__global__ void __launch_bounds__(256) ssm_kernel(
    const float* __restrict__ pp, const float* __restrict__ state,
    const float* __restrict__ A_log, const float* __restrict__ Dvec,
    float* __restrict__ h_out, float* __restrict__ g, float* __restrict__ out) {
    if (blockIdx.x < D_MODEL / 256)
        out[blockIdx.x * 256 + threadIdx.x] = 0.f;

    const int wave  = threadIdx.x >> 6;
    const int lane  = threadIdx.x & 63;
    const int group = lane >> 4;
    const int sl    = lane & 15;
    const int d     = blockIdx.x * 16 + wave * 4 + group;

    float dt_raw = 0.f, z = 0.f, xr = 0.f;
    f32x4 Bv = {0.f, 0.f, 0.f, 0.f}, Cv = {0.f, 0.f, 0.f, 0.f};
    #pragma unroll
    for (int p = 0; p < NSEG1; ++p) {
        const float* b = pp + p * PP1_STRIDE;
        dt_raw += b[2 * D_INNER + 2 * D_STATE];
        z      += b[d];
        xr     += b[D_INNER + d];
        f32x4 bb = *reinterpret_cast<const f32x4*>(b + 2 * D_INNER + 4 * sl);
        f32x4 cc = *reinterpret_cast<const f32x4*>(b + 2 * D_INNER + D_STATE + 4 * sl);
        Bv += bb; Cv += cc;
    }
    const float dt = (dt_raw > 20.f) ? dt_raw : log1pf(expf(dt_raw));
    const f32x4 Al = *reinterpret_cast<const f32x4*>(A_log + 4 * sl);
    const float x_ssm = xr / (1.f + expf(-xr));

    const f32x4 st = *reinterpret_cast<const f32x4*>(state + (size_t)d * D_STATE + 4 * sl);
    f32x4 h;
    h.x = st.x * expf(-expf(Al.x) * dt) + x_ssm * (dt * Bv.x);
    h.y = st.y * expf(-expf(Al.y) * dt) + x_ssm * (dt * Bv.y);
    h.z = st.z * expf(-expf(Al.z) * dt) + x_ssm * (dt * Bv.z);
    h.w = st.w * expf(-expf(Al.w) * dt) + x_ssm * (dt * Bv.w);
    *reinterpret_cast<f32x4*>(h_out + (size_t)d * D_STATE + 4 * sl) = h;

    float yv = h.x * Cv.x + h.y * Cv.y + h.z * Cv.z + h.w * Cv.w;
    #pragma unroll
    for (int off = 8; off; off >>= 1) yv += __shfl_xor(yv, off, 64);
    if (sl == 0) {
        const float y = yv + Dvec[d] * x_ssm;
        g[d] = y * (z / (1.f + expf(-z)));
    }
}

// ---------------------------------------------------------------------------
// Kernel 3: out += W_out @ g, column-split 8 ways (1024-col segments),
// accumulated via atomicAdd (8 adds/output; out pre-zeroed by kernel 2).
// ---------------------------------------------------------------------------
__global__ void __launch_bounds__(256) matvec_out_kernel(
    const float* __restrict__ W, const float* __restrict__ g,
    float* __restrict__ out) {
    const int wave = threadIdx.x >> 6;
    const int lane = threadIdx.x & 63;
    const int seg  = blockIdx.x & (NSEG3 - 1);
    const int pair = (blockIdx.x >> 3) * 4 + wave;
    const int row0 = pair * 2;
    const int row1 = row0 + 1;

    const int k0 = seg * (D_INNER / NSEG3);  // 1024-col segment
    const float* Wr0 = W + (size_t)row0 * D_INNER + k0;
    const float* Wr1 = Wr0 + D_INNER;
    const float* gp  = g + k0;

    float acc0 = 0.f, acc1 = 0.f;
    #pragma unroll
    for (int k = lane * 4; k < D_INNER / NSEG3; k += 64 * 4) {
        f32x4 xv = *reinterpret_cast<const f32x4*>(gp + k);
        f32x4 w0 = *reinterpret_cast<const f32x4*>(Wr0 + k);
        f32x4 w1 = *reinterpret_cast<const f32x4*>(Wr1 + k);
        acc0 += w0.x * xv.x + w0.y * xv.y + w0.z * xv.z + w0.w * xv.w;
        acc1 += w1.x * xv.x + w1.y * xv.y + w1.z * xv.z + w1.w * xv.w;
    }
    #pragma unroll
    for (int off = 32; off; off >>= 1) {
        acc0 += __shfl_down(acc0, off, 64);
        acc1 += __shfl_down(acc1, off, 64);
    }
    if (lane == 0) {
        atomicAdd(&out[row0], acc0);
        atomicAdd(&out[row1], acc1);
    }
}

extern "C" void kernel_launch(void* const* d_in, const int* in_sizes, int n_in,
                              void* d_out, int out_size, void* d_ws, size_t ws_size,
                              hipStream_t stream) {
    const float* x     = (const float*)d_in[0];
    const float* state = (const float*)d_in[1];
    const float* W_in  = (const float*)d_in[2];
    const float* A_log = (const float*)d_in[3];
    const float* Dvec  = (const float*)d_in[4];
    const float* W_out = (const float*)d_in[5];

    float* out   = (float*)d_out;          // [4096]
    float* h_out = out + D_MODEL;          // [8192*64]

    float* pp = (float*)d_ws;              // [4][16516] proj partials
    float* g  = pp + G_OFF;                // [8192]

    matvec_in_kernel<<<2065 * NSEG1, 256, 0, stream>>>(W_in, x, pp);
    ssm_kernel<<<D_INNER / 16, 256, 0, stream>>>(pp, state, A_log, Dvec, h_out, g, out);
    matvec_out_kernel<<<512 * NSEG3, 256, 0, stream>>>(W_out, g, out);
}

// Round 9
// 71.778 us; speedup vs baseline: 1.0874x; 1.0874x over previous
//
#include <hip/hip_runtime.h>
#include <math.h>

#define D_MODEL 4096
#define D_INNER 8192
#define D_STATE 64
#define PROJ_OUT (2 * D_INNER + 2 * D_STATE + 1)  // 16513

typedef float f32x4 __attribute__((ext_vector_type(4)));

// ws layout (floats):
#define NSEG1 4
#define PP1_STRIDE 16516                 // PROJ_OUT padded to x4
#define G_OFF (NSEG1 * PP1_STRIDE)       // 66064
#define NSEG3 8

// ---------------------------------------------------------------------------
// Kernel 1: proj partials = W_in @ x, column-split 4 ways (1024-col segments).
// NT loads on W_in are REQUIRED (A/B round 7 vs 8: 71.4 vs 78.1 µs): the
// single-use 270 MB stream must bypass L3 so W_out stays LLC-resident for k3.
// ---------------------------------------------------------------------------
__global__ void __launch_bounds__(256) matvec_in_kernel(
    const float* __restrict__ W, const float* __restrict__ x,
    float* __restrict__ pp) {
    const int wave = threadIdx.x >> 6;
    const int lane = threadIdx.x & 63;
    const int seg  = blockIdx.x & (NSEG1 - 1);
    const int pair = (blockIdx.x >> 2) * 4 + wave;
    const int row0 = pair * 2;
    if (row0 >= PROJ_OUT) return;
    const int row1 = row0 + 1;
    const bool has1 = (row1 < PROJ_OUT);

    const int k0 = seg * (D_MODEL / NSEG1);  // 1024-col segment
    const float* Wr0 = W + (size_t)row0 * D_MODEL + k0;
    const float* Wr1 = has1 ? (Wr0 + D_MODEL) : Wr0;
    const float* xp  = x + k0;

    float acc0 = 0.f, acc1 = 0.f;
    #pragma unroll
    for (int k = lane * 4; k < D_MODEL / NSEG1; k += 64 * 4) {
        f32x4 xv = *reinterpret_cast<const f32x4*>(xp + k);
        f32x4 w0 = __builtin_nontemporal_load(reinterpret_cast<const f32x4*>(Wr0 + k));
        f32x4 w1 = __builtin_nontemporal_load(reinterpret_cast<const f32x4*>(Wr1 + k));
        acc0 += w0.x * xv.x + w0.y * xv.y + w0.z * xv.z + w0.w * xv.w;
        acc1 += w1.x * xv.x + w1.y * xv.y + w1.z * xv.z + w1.w * xv.w;
    }
    #pragma unroll
    for (int off = 32; off; off >>= 1) {
        acc0 += __shfl_down(acc0, off, 64);
        acc1 += __shfl_down(acc1, off, 64);
    }
    if (lane == 0) {
        pp[seg * PP1_STRIDE + row0] = acc0;
        if (has1) pp[seg * PP1_STRIDE + row1] = acc1;
    }
}

// ---------------------------------------------------------------------------
// Kernel 2: SSM update + gating; folds the 4 column-partials inline.
// Blocks 0..15 also zero out[0:4096] so kernel 3 can atomically accumulate.
// ---------------------------------------------------------------------------
__global__ void __launch_bounds__(256) ssm_kernel(
    const float* __restrict__ pp, const float* __restrict__ state,
    const float* __restrict__ A_log, const float* __restrict__ Dvec,
    float* __restrict__ h_out, float* __restrict__ g, float* __restrict__ out) {
    if (blockIdx.x < D_MODEL / 256)
        out[blockIdx.x * 256 + threadIdx.x] = 0.f;

    const int wave  = threadIdx.x >> 6;
    const int lane  = threadIdx.x & 63;
    const int group = lane >> 4;
    const int sl    = lane & 15;
    const int d     = blockIdx.x * 16 + wave * 4 + group;

    float dt_raw = 0.f, z = 0.f, xr = 0.f;
    f32x4 Bv = {0.f, 0.f, 0.f, 0.f}, Cv = {0.f, 0.f, 0.f, 0.f};
    #pragma unroll
    for (int p = 0; p < NSEG1; ++p) {
        const float* b = pp + p * PP1_STRIDE;
        dt_raw += b[2 * D_INNER + 2 * D_STATE];
        z      += b[d];
        xr     += b[D_INNER + d];
        f32x4 bb = *reinterpret_cast<const f32x4*>(b + 2 * D_INNER + 4 * sl);
        f32x4 cc = *reinterpret_cast<const f32x4*>(b + 2 * D_INNER + D_STATE + 4 * sl);
        Bv += bb; Cv += cc;
    }
    const float dt = (dt_raw > 20.f) ? dt_raw : log1pf(expf(dt_raw));
    const f32x4 Al = *reinterpret_cast<const f32x4*>(A_log + 4 * sl);
    const float x_ssm = xr / (1.f + expf(-xr));

    const f32x4 st = *reinterpret_cast<const f32x4*>(state + (size_t)d * D_STATE + 4 * sl);
    f32x4 h;
    h.x = st.x * expf(-expf(Al.x) * dt) + x_ssm * (dt * Bv.x);
    h.y = st.y * expf(-expf(Al.y) * dt) + x_ssm * (dt * Bv.y);
    h.z = st.z * expf(-expf(Al.z) * dt) + x_ssm * (dt * Bv.z);
    h.w = st.w * expf(-expf(Al.w) * dt) + x_ssm * (dt * Bv.w);
    *reinterpret_cast<f32x4*>(h_out + (size_t)d * D_STATE + 4 * sl) = h;

    float yv = h.x * Cv.x + h.y * Cv.y + h.z * Cv.z + h.w * Cv.w;
    #pragma unroll
    for (int off = 8; off; off >>= 1) yv += __shfl_xor(yv, off, 64);
    if (sl == 0) {
        const float y = yv + Dvec[d] * x_ssm;
        g[d] = y * (z / (1.f + expf(-z)));
    }
}

// ---------------------------------------------------------------------------
// Kernel 3: out += W_out @ g, column-split 8 ways (1024-col segments),
// accumulated via atomicAdd (8 adds/output; out pre-zeroed by kernel 2).
// Plain (cached) loads: W_out is L3-resident across graph replays.
// ---------------------------------------------------------------------------
__global__ void __launch_bounds__(256) matvec_out_kernel(
    const float* __restrict__ W, const float* __restrict__ g,
    float* __restrict__ out) {
    const int wave = threadIdx.x >> 6;
    const int lane = threadIdx.x & 63;
    const int seg  = blockIdx.x & (NSEG3 - 1);
    const int pair = (blockIdx.x >> 3) * 4 + wave;
    const int row0 = pair * 2;
    const int row1 = row0 + 1;

    const int k0 = seg * (D_INNER / NSEG3);  // 1024-col segment
    const float* Wr0 = W + (size_t)row0 * D_INNER + k0;
    const float* Wr1 = Wr0 + D_INNER;
    const float* gp  = g + k0;

    float acc0 = 0.f, acc1 = 0.f;
    #pragma unroll
    for (int k = lane * 4; k < D_INNER / NSEG3; k += 64 * 4) {
        f32x4 xv = *reinterpret_cast<const f32x4*>(gp + k);
        f32x4 w0 = *reinterpret_cast<const f32x4*>(Wr0 + k);
        f32x4 w1 = *reinterpret_cast<const f32x4*>(Wr1 + k);
        acc0 += w0.x * xv.x + w0.y * xv.y + w0.z * xv.z + w0.w * xv.w;
        acc1 += w1.x * xv.x + w1.y * xv.y + w1.z * xv.z + w1.w * xv.w;
    }
    #pragma unroll
    for (int off = 32; off; off >>= 1) {
        acc0 += __shfl_down(acc0, off, 64);
        acc1 += __shfl_down(acc1, off, 64);
    }
    if (lane == 0) {
        atomicAdd(&out[row0], acc0);
        atomicAdd(&out[row1], acc1);
    }
}

extern "C" void kernel_launch(void* const* d_in, const int* in_sizes, int n_in,
                              void* d_out, int out_size, void* d_ws, size_t ws_size,
                              hipStream_t stream) {
    const float* x     = (const float*)d_in[0];
    const float* state = (const float*)d_in[1];
    const float* W_in  = (const float*)d_in[2];
    const float* A_log = (const float*)d_in[3];
    const float* Dvec  = (const float*)d_in[4];
    const float* W_out = (const float*)d_in[5];

    float* out   = (float*)d_out;          // [4096]
    float* h_out = out + D_MODEL;          // [8192*64]

    float* pp = (float*)d_ws;              // [4][16516] proj partials
    float* g  = pp + G_OFF;                // [8192]

    matvec_in_kernel<<<2065 * NSEG1, 256, 0, stream>>>(W_in, x, pp);
    ssm_kernel<<<D_INNER / 16, 256, 0, stream>>>(pp, state, A_log, Dvec, h_out, g, out);
    matvec_out_kernel<<<512 * NSEG3, 256, 0, stream>>>(W_out, g, out);
}